// Round 9
// baseline (186.091 us; speedup 1.0000x reference)
//
#include <hip/hip_runtime.h>
#include <hip/hip_bf16.h>

// B=2, S=2048, D=1024, H=16, hd=64.
// cast -> fused QKV GEMM (Q row-major pre-scaled by 0.125*log2e; K row-major;
// V transposed to Vt[b,h,d,s]) -> mask bitpack -> flash attention
// (2 waves/32 q-rows per block for 7-8 independent barrier groups/CU,
//  XOR-swizzled K/V LDS, swapped QK^T, cvt_pk P->bf16, contiguous b32 P
//  stores; no max-tracking: P=exp2(S) masked->0, l via ones-MFMA) -> out GEMM.
// Workspace (needs 65 MiB):
//   [0,8M) q bf16 [8,16M) k bf16 [16,24M) v bf16
//   [24,26M) Wq [26,28M) Wk [28,30M) Wv [30,32M) Wo   (bf16)
//   [32,40M) Q bf16  [40,48M) K bf16  [48,56M) Vt bf16 [b,h,d,s]
//   [56,64M) attn-out bf16   [64M, 65M) mask bits u64

typedef float f32x4 __attribute__((ext_vector_type(4)));
typedef short s16x8 __attribute__((ext_vector_type(8)));

#if __has_builtin(__builtin_amdgcn_exp2f)
#define EXP2F __builtin_amdgcn_exp2f
#else
#define EXP2F exp2f
#endif

#define P_STR 78
// XOR swizzle for [64][64] bf16 LDS tiles: col8 in units of 8 elems (16B)
#define KSWZ(row, col8) ((row) * 64 + ((col8) ^ (((row) & 7) << 3)))

__device__ __forceinline__ void gload16(const void* g, void* l) {
  __builtin_amdgcn_global_load_lds(
      (const __attribute__((address_space(1))) unsigned int*)g,
      (__attribute__((address_space(3))) unsigned int*)l, 16, 0, 0);
}

__device__ __forceinline__ f32x4 mfma16x16x32(s16x8 a, s16x8 b, f32x4 c) {
  return __builtin_amdgcn_mfma_f32_16x16x32_bf16(a, b, c, 0, 0, 0);
}

__device__ __forceinline__ unsigned short bf16bits(float x) {
  __hip_bfloat16 h = __float2bfloat16(x);
  return *reinterpret_cast<unsigned short*>(&h);
}

// pack 2 f32 -> 2 bf16 (RNE), single instruction
__device__ __forceinline__ unsigned cvt_pk_bf16(float lo, float hi) {
  unsigned r;
  asm("v_cvt_pk_bf16_f32 %0, %1, %2" : "=v"(r) : "v"(lo), "v"(hi));
  return r;
}

// --- fused casts ---------------------------------------------------------
__global__ void cast3_kernel(const float* __restrict__ a,
                             const float* __restrict__ b,
                             const float* __restrict__ c,
                             __hip_bfloat16* oa, __hip_bfloat16* ob,
                             __hip_bfloat16* oc, int n4) {
  int i = blockIdx.x * blockDim.x + threadIdx.x;
  if (i >= n4) return;
  const float* in = blockIdx.y == 0 ? a : (blockIdx.y == 1 ? b : c);
  __hip_bfloat16* out = blockIdx.y == 0 ? oa : (blockIdx.y == 1 ? ob : oc);
  float4 v = ((const float4*)in)[i];
  ushort4 o;
  o.x = bf16bits(v.x);
  o.y = bf16bits(v.y);
  o.z = bf16bits(v.z);
  o.w = bf16bits(v.w);
  ((ushort4*)out)[i] = o;
}

__global__ void cast4_kernel(const float* __restrict__ a,
                             const float* __restrict__ b,
                             const float* __restrict__ c,
                             const float* __restrict__ d, __hip_bfloat16* oa,
                             __hip_bfloat16* ob, __hip_bfloat16* oc,
                             __hip_bfloat16* od, int n4) {
  int i = blockIdx.x * blockDim.x + threadIdx.x;
  if (i >= n4) return;
  const float* in = blockIdx.y == 0 ? a
                    : blockIdx.y == 1 ? b
                    : blockIdx.y == 2 ? c
                                      : d;
  __hip_bfloat16* out = blockIdx.y == 0 ? oa
                        : blockIdx.y == 1 ? ob
                        : blockIdx.y == 2 ? oc
                                          : od;
  float4 v = ((const float4*)in)[i];
  ushort4 o;
  o.x = bf16bits(v.x);
  o.y = bf16bits(v.y);
  o.z = bf16bits(v.z);
  o.w = bf16bits(v.w);
  ((ushort4*)out)[i] = o;
}

// --- mask -> bits: word gw covers mask[gw*64 .. gw*64+63] ----------------
__global__ void mask_bits_kernel(const int* __restrict__ mask,
                                 unsigned long long* __restrict__ bits) {
  int gw = (blockIdx.x * blockDim.x + threadIdx.x) >> 6;
  int lane = threadIdx.x & 63;
  int mv = mask[(size_t)gw * 64 + lane];
  unsigned long long b = __ballot(mv != 0);
  if (lane == 0) bits[gw] = b;
}

// --- fused QKV GEMM ------------------------------------------------------
// z=0: Qp = (q@Wq^T+bq)*0.125*log2e   (row-major bf16)
// z=1: Kp = (k@Wk^T+bk)               (row-major bf16)
// z=2: Vt = (v@Wv^T+bv) transposed to Vt[b,h,d,s]
__global__ __launch_bounds__(256) void gemm_qkv(
    const __hip_bfloat16* __restrict__ qb,
    const __hip_bfloat16* __restrict__ kb,
    const __hip_bfloat16* __restrict__ vb,
    const __hip_bfloat16* __restrict__ wq,
    const __hip_bfloat16* __restrict__ wk,
    const __hip_bfloat16* __restrict__ wv, const float* __restrict__ bq,
    const float* __restrict__ bk_, const float* __restrict__ bv_,
    __hip_bfloat16* __restrict__ Qp, __hip_bfloat16* __restrict__ Kp,
    __hip_bfloat16* __restrict__ Vtp) {
  constexpr int N = 1024, K = 1024;
  // XCD-chunked swizzle over flattened grid (8 x, 32 y, 3 z) = 768
  const int fid = blockIdx.x + 8 * (blockIdx.y + 32 * blockIdx.z);
  const int nid = (fid & 7) * 96 + (fid >> 3);
  const int bx = nid & 7;
  const int by = (nid >> 3) & 31;
  const int z = nid >> 8;

  const __hip_bfloat16* A = z == 0 ? qb : z == 1 ? kb : vb;
  const __hip_bfloat16* Bw = z == 0 ? wq : z == 1 ? wk : wv;
  const float* bias = z == 0 ? bq : z == 1 ? bk_ : bv_;

  __shared__ __hip_bfloat16 sA[128 * 32];
  __shared__ __hip_bfloat16 sB[128 * 32];
  const int tid = threadIdx.x;
  const int lane = tid & 63;
  const int wid = tid >> 6;
  const int wr = wid >> 1;
  const int wc = wid & 1;
  const int m0 = by * 128;
  const int n0 = bx * 128;
  const int srow = tid >> 2;
  const int scol = (tid & 3) * 8;

  f32x4 acc[4][4] = {};
  const int fr = lane & 15;
  const int fk = (lane >> 4) * 8;

  for (int k0 = 0; k0 < K; k0 += 32) {
    gload16(A + (size_t)(m0 + srow) * K + k0 + scol, sA + tid * 8);
    gload16(A + (size_t)(m0 + 64 + srow) * K + k0 + scol, sA + 2048 + tid * 8);
    gload16(Bw + (size_t)(n0 + srow) * K + k0 + scol, sB + tid * 8);
    gload16(Bw + (size_t)(n0 + 64 + srow) * K + k0 + scol, sB + 2048 + tid * 8);
    __syncthreads();
    s16x8 af[4], bfr[4];
#pragma unroll
    for (int mi = 0; mi < 4; ++mi)
      af[mi] = *(const s16x8*)(sA + (wr * 64 + mi * 16 + fr) * 32 + fk);
#pragma unroll
    for (int ni = 0; ni < 4; ++ni)
      bfr[ni] = *(const s16x8*)(sB + (wc * 64 + ni * 16 + fr) * 32 + fk);
#pragma unroll
    for (int mi = 0; mi < 4; ++mi)
#pragma unroll
      for (int ni = 0; ni < 4; ++ni)
        acc[mi][ni] = mfma16x16x32(af[mi], bfr[ni], acc[mi][ni]);
    __syncthreads();
  }

  const int fq = (lane >> 4) * 4;
#pragma unroll
  for (int mi = 0; mi < 4; ++mi) {
#pragma unroll
    for (int ni = 0; ni < 4; ++ni) {
      const int row = m0 + wr * 64 + mi * 16 + fq;
      const int col = n0 + wc * 64 + ni * 16 + fr;
      const float bv = bias[col];
      f32x4 v = acc[mi][ni];
      if (z == 2) {
        ushort4 pk;
        pk.x = bf16bits(v[0] + bv);
        pk.y = bf16bits(v[1] + bv);
        pk.z = bf16bits(v[2] + bv);
        pk.w = bf16bits(v[3] + bv);
        const int bb = row >> 11;
        const int s = row & 2047;
        size_t vtrow = ((size_t)(bb * 16) + (col >> 6)) * 64 + (col & 63);
        *(ushort4*)(Vtp + vtrow * 2048 + s) = pk;
      } else if (z == 1) {
#pragma unroll
        for (int r = 0; r < 4; ++r)
          Kp[(size_t)(row + r) * N + col] = __float2bfloat16(v[r] + bv);
      } else {
#pragma unroll
        for (int r = 0; r < 4; ++r)
          Qp[(size_t)(row + r) * N + col] =
              __float2bfloat16((v[r] + bv) * 0.18033688f);  // 0.125*log2(e)
      }
    }
  }
}

// --- out GEMM: C = A @ Bw^T + bias (f32 out) -----------------------------
__global__ __launch_bounds__(256) void gemm_out(
    const __hip_bfloat16* __restrict__ A, const __hip_bfloat16* __restrict__ Bw,
    const float* __restrict__ bias, float* __restrict__ Cout) {
  constexpr int N = 1024, K = 1024;
  const int fid = blockIdx.x + 8 * blockIdx.y;
  const int nid = (fid & 7) * 32 + (fid >> 3);
  const int bx = nid & 7;
  const int by = nid >> 3;

  __shared__ __hip_bfloat16 sA[128 * 32];
  __shared__ __hip_bfloat16 sB[128 * 32];
  const int tid = threadIdx.x;
  const int lane = tid & 63;
  const int wid = tid >> 6;
  const int wr = wid >> 1;
  const int wc = wid & 1;
  const int m0 = by * 128;
  const int n0 = bx * 128;
  const int srow = tid >> 2;
  const int scol = (tid & 3) * 8;

  f32x4 acc[4][4] = {};
  const int fr = lane & 15;
  const int fk = (lane >> 4) * 8;

  for (int k0 = 0; k0 < K; k0 += 32) {
    gload16(A + (size_t)(m0 + srow) * K + k0 + scol, sA + tid * 8);
    gload16(A + (size_t)(m0 + 64 + srow) * K + k0 + scol, sA + 2048 + tid * 8);
    gload16(Bw + (size_t)(n0 + srow) * K + k0 + scol, sB + tid * 8);
    gload16(Bw + (size_t)(n0 + 64 + srow) * K + k0 + scol, sB + 2048 + tid * 8);
    __syncthreads();
    s16x8 af[4], bfr[4];
#pragma unroll
    for (int mi = 0; mi < 4; ++mi)
      af[mi] = *(const s16x8*)(sA + (wr * 64 + mi * 16 + fr) * 32 + fk);
#pragma unroll
    for (int ni = 0; ni < 4; ++ni)
      bfr[ni] = *(const s16x8*)(sB + (wc * 64 + ni * 16 + fr) * 32 + fk);
#pragma unroll
    for (int mi = 0; mi < 4; ++mi)
#pragma unroll
      for (int ni = 0; ni < 4; ++ni)
        acc[mi][ni] = mfma16x16x32(af[mi], bfr[ni], acc[mi][ni]);
    __syncthreads();
  }

  const int fq = (lane >> 4) * 4;
#pragma unroll
  for (int mi = 0; mi < 4; ++mi) {
#pragma unroll
    for (int ni = 0; ni < 4; ++ni) {
      const int row = m0 + wr * 64 + mi * 16 + fq;
      const int col = n0 + wc * 64 + ni * 16 + fr;
      const float bv = bias[col];
      f32x4 v = acc[mi][ni];
#pragma unroll
      for (int r = 0; r < 4; ++r)
        Cout[(size_t)(row + r) * N + col] = v[r] + bv;
    }
  }
}

// --- flash attention (2 waves / 32 q-rows, swizzled LDS, swapped QK^T) ---
// One block = (b,h) x 32 q-rows; wave w owns q rows [w*16, w*16+16).
// Grid 2048 -> 7-8 independent barrier groups per CU (latency hiding).
// Swapped: sc = mfma(K_frag, Q_frag) => D[kv][q]: lane holds q = fr fixed,
// kv = ni*16 + fq + r. Mask = one u64 per lane per tile. P packed to bf16
// via v_cvt_pk_bf16_f32, stored as contiguous b32 into [q][kv] LDS.
// l = P @ ones via MFMA (rows = q, matches o rows).
__global__ __launch_bounds__(128) void attn_kernel(
    const __hip_bfloat16* __restrict__ Q, const __hip_bfloat16* __restrict__ Kb,
    const __hip_bfloat16* __restrict__ Vt,
    const unsigned long long* __restrict__ gbits,
    __hip_bfloat16* __restrict__ O, int S) {
  __shared__ __hip_bfloat16 sK[64 * 64];   // [kv][d] swizzled
  __shared__ __hip_bfloat16 sVT[64 * 64];  // [d][kv] swizzled
  __shared__ unsigned short sP[2][16 * P_STR];

  const int tid = threadIdx.x;  // 0..127
  const int lane = tid & 63;
  const int wid = tid >> 6;  // 0..1
  // XCD-chunked swizzle: grid (64,32)=2048, 256 blocks (4 heads) per XCD
  const int fid = blockIdx.x + 64 * blockIdx.y;
  const int nid = (fid & 7) * 256 + (fid >> 3);
  const int qblk = nid & 63;
  const int bh = nid >> 6;
  const int q0 = qblk * 32;
  const int b = bh >> 4;
  const size_t rowbase = (size_t)b * S * 1024 + (size_t)(bh & 15) * 64;
  const size_t vtbase = (size_t)bh * 64;

  const int srow = tid >> 3;       // 0..15
  const int scol = (tid & 7) * 8;  // 0..56

  const int fr = lane & 15;
  const int fk = (lane >> 4) * 8;
  const int fq = (lane >> 4) * 4;

  // Q fragments direct from global (one-time)
  const s16x8 aq0 =
      *(const s16x8*)(Q + rowbase + (size_t)(q0 + wid * 16 + fr) * 1024 + fk);
  const s16x8 aq1 = *(const s16x8*)(Q + rowbase +
                                    (size_t)(q0 + wid * 16 + fr) * 1024 + 32 +
                                    fk);

  f32x4 o[4] = {};
  f32x4 lacc = {};
  s16x8 ones;
#pragma unroll
  for (int j = 0; j < 8; ++j) ones[j] = (short)0x3F80;  // bf16 1.0

  // one mask row per lane: q = q0 + wid*16 + fr
  const unsigned long long* bitrow =
      gbits + ((size_t)b * S + q0 + wid * 16 + fr) * (S / 64);

  // prologue: prefetch tile 0 into regs (4 row-chunks of 16 for K and V)
  s16x8 kr[4], vr[4];
#pragma unroll
  for (int c = 0; c < 4; ++c) {
    const int row = c * 16 + srow;
    kr[c] = *(const s16x8*)(Kb + rowbase + (size_t)row * 1024 + scol);
    vr[c] = *(const s16x8*)(Vt + (vtbase + row) * 2048 + scol);
  }
  unsigned long long wcur = bitrow[0], wnxt = 0;

  unsigned short* pw = &sP[wid][0];
  const int ntiles = S / 64;

  for (int t = 0; t < ntiles; ++t) {
    __syncthreads();  // all waves done reading previous tile
#pragma unroll
    for (int c = 0; c < 4; ++c) {
      const int row = c * 16 + srow;
      *(s16x8*)(sK + KSWZ(row, scol)) = kr[c];
      *(s16x8*)(sVT + KSWZ(row, scol)) = vr[c];
    }
    __syncthreads();  // tile ready

    // next-tile loads issued after the barrier -> hide under compute
    if (t + 1 < ntiles) {
      const int kv = (t + 1) * 64;
#pragma unroll
      for (int c = 0; c < 4; ++c) {
        const int row = c * 16 + srow;
        kr[c] =
            *(const s16x8*)(Kb + rowbase + (size_t)(kv + row) * 1024 + scol);
        vr[c] = *(const s16x8*)(Vt + (vtbase + row) * 2048 + kv + scol);
      }
      wnxt = bitrow[t + 1];
    }

    // S^T = K Q^T (swapped): sc[ni][r] = S[kv=ni*16+fq+r][q=fr]
    f32x4 sc[4];
#pragma unroll
    for (int ni = 0; ni < 4; ++ni) {
      s16x8 bk0 = *(const s16x8*)(sK + KSWZ(ni * 16 + fr, fk));
      s16x8 bk1 = *(const s16x8*)(sK + KSWZ(ni * 16 + fr, 32 + fk));
      f32x4 z = {};
      z = mfma16x16x32(bk0, aq0, z);
      z = mfma16x16x32(bk1, aq1, z);
      sc[ni] = z;
    }

    // P = mask ? exp2(S) : 0; pack pairs; contiguous b32 stores to [q][kv]
    const unsigned mlo = (unsigned)(wcur >> fq);
    const unsigned mhi = (unsigned)(wcur >> (fq + 32));
    wcur = wnxt;
#pragma unroll
    for (int ni = 0; ni < 4; ++ni) {
      const unsigned src = (ni & 2) ? mhi : mlo;
      const int base = (ni & 1) * 16;
      float p0 = EXP2F(sc[ni][0]);
      float p1 = EXP2F(sc[ni][1]);
      float p2 = EXP2F(sc[ni][2]);
      float p3 = EXP2F(sc[ni][3]);
      p0 = ((src >> (base + 0)) & 1u) ? p0 : 0.f;
      p1 = ((src >> (base + 1)) & 1u) ? p1 : 0.f;
      p2 = ((src >> (base + 2)) & 1u) ? p2 : 0.f;
      p3 = ((src >> (base + 3)) & 1u) ? p3 : 0.f;
      unsigned w0 = cvt_pk_bf16(p0, p1);
      unsigned w1 = cvt_pk_bf16(p2, p3);
      *(unsigned*)(pw + fr * P_STR + ni * 16 + fq) = w0;
      *(unsigned*)(pw + fr * P_STR + ni * 16 + fq + 2) = w1;
    }

    s16x8 ap0 = *(const s16x8*)(pw + fr * P_STR + fk);
    s16x8 ap1 = *(const s16x8*)(pw + fr * P_STR + 32 + fk);
    lacc = mfma16x16x32(ap0, ones, lacc);
    lacc = mfma16x16x32(ap1, ones, lacc);
#pragma unroll
    for (int nd = 0; nd < 4; ++nd) {
      s16x8 bv0 = *(const s16x8*)(sVT + KSWZ(nd * 16 + fr, fk));
      s16x8 bv1 = *(const s16x8*)(sVT + KSWZ(nd * 16 + fr, 32 + fk));
      o[nd] = mfma16x16x32(ap0, bv0, o[nd]);
      o[nd] = mfma16x16x32(ap1, bv1, o[nd]);
    }
  }

  float inv[4];
#pragma unroll
  for (int r = 0; r < 4; ++r) inv[r] = 1.0f / lacc[r];
#pragma unroll
  for (int nd = 0; nd < 4; ++nd)
#pragma unroll
    for (int r = 0; r < 4; ++r) {
      float x = o[nd][r] * inv[r];
      O[rowbase + (size_t)(q0 + wid * 16 + fq + r) * 1024 + nd * 16 + fr] =
          __float2bfloat16(x);
    }
}

extern "C" void kernel_launch(void* const* d_in, const int* in_sizes, int n_in,
                              void* d_out, int out_size, void* d_ws,
                              size_t ws_size, hipStream_t stream) {
  const float* query = (const float*)d_in[0];
  const float* key = (const float*)d_in[1];
  const float* value = (const float*)d_in[2];
  const int* mask = (const int*)d_in[3];
  const float* Wq = (const float*)d_in[4];
  const float* bq = (const float*)d_in[5];
  const float* Wk = (const float*)d_in[6];
  const float* bk = (const float*)d_in[7];
  const float* Wv = (const float*)d_in[8];
  const float* bv = (const float*)d_in[9];
  const float* Wo = (const float*)d_in[10];
  const float* bo = (const float*)d_in[11];

  const int B = 2, S = 2048, D = 1024;
  const int M = B * S;
  const size_t MB = 1024u * 1024u;

  char* ws = (char*)d_ws;
  __hip_bfloat16* qb = (__hip_bfloat16*)(ws + 0 * MB);
  __hip_bfloat16* kb = (__hip_bfloat16*)(ws + 8 * MB);
  __hip_bfloat16* vb = (__hip_bfloat16*)(ws + 16 * MB);
  __hip_bfloat16* wqb = (__hip_bfloat16*)(ws + 24 * MB);
  __hip_bfloat16* wkb = (__hip_bfloat16*)(ws + 26 * MB);
  __hip_bfloat16* wvb = (__hip_bfloat16*)(ws + 28 * MB);
  __hip_bfloat16* wob = (__hip_bfloat16*)(ws + 30 * MB);
  __hip_bfloat16* Qp = (__hip_bfloat16*)(ws + 32 * MB);
  __hip_bfloat16* Kp = (__hip_bfloat16*)(ws + 40 * MB);
  __hip_bfloat16* Vtp = (__hip_bfloat16*)(ws + 48 * MB);
  __hip_bfloat16* Ob = (__hip_bfloat16*)(ws + 56 * MB);
  unsigned long long* bits = (unsigned long long*)(ws + 64 * MB);

  {
    int n4 = (int)((size_t)M * D / 4);
    cast3_kernel<<<dim3((n4 + 255) / 256, 3), dim3(256), 0, stream>>>(
        query, key, value, qb, kb, vb, n4);
  }
  {
    int n4 = (int)((size_t)D * D / 4);
    cast4_kernel<<<dim3((n4 + 255) / 256, 4), dim3(256), 0, stream>>>(
        Wq, Wk, Wv, Wo, wqb, wkb, wvb, wob, n4);
  }
  {
    int words = B * S * (S / 64);  // 131072
    mask_bits_kernel<<<dim3(words / 4), dim3(256), 0, stream>>>(mask, bits);
  }

  gemm_qkv<<<dim3(D / 128, M / 128, 3), dim3(256), 0, stream>>>(
      qb, kb, vb, wqb, wkb, wvb, bq, bk, bv, Qp, Kp, Vtp);

  attn_kernel<<<dim3(S / 32, B * 16), dim3(128), 0, stream>>>(Qp, Kp, Vtp,
                                                              bits, Ob, S);

  gemm_out<<<dim3(D / 128, M / 128), dim3(256), 0, stream>>>(Ob, wob, bo,
                                                             (float*)d_out);
}

// Round 11
// 148.769 us; speedup vs baseline: 1.2509x; 1.2509x over previous
//
#include <hip/hip_runtime.h>
#include <hip/hip_bf16.h>

// B=2, S=2048, D=1024, H=16, hd=64.
// cast -> fused QKV GEMM (Q row-major pre-scaled by 0.125*log2e; K row-major;
// V transposed to Vt[b,h,d,s]) -> mask bitpack -> flash attention with
// 32x32x16 MFMA + IN-REGISTER softmax (cvt_pk + permlane32_swap, no P LDS),
// K/V via global_load_lds with pre-swizzled source, dbuf, 1 barrier/tile,
// no max-tracking (P=exp2(S) masked->0, l via ones-MFMA) -> out GEMM.
// R11: fixed permlane32_swap operand order (d.hi <-> s.lo; d must be the
// b_-even word so lo lanes keep their own words and receive partner's hi).

typedef float f32x4 __attribute__((ext_vector_type(4)));
typedef float f32x16 __attribute__((ext_vector_type(16)));
typedef short s16x8 __attribute__((ext_vector_type(8)));
typedef unsigned u32x4 __attribute__((ext_vector_type(4)));

#if __has_builtin(__builtin_amdgcn_exp2f)
#define EXP2F __builtin_amdgcn_exp2f
#else
#define EXP2F exp2f
#endif

#if __has_builtin(__builtin_amdgcn_rcpf)
#define RCPF __builtin_amdgcn_rcpf
#else
#define RCPF(x) (1.0f / (x))
#endif

// XOR swizzle for [64][64] bf16 LDS tiles: e = element col offset (mult of 8)
#define KSWZ(row, e) ((row) * 64 + ((e) ^ (((row) & 7) << 3)))

__device__ __forceinline__ void gload16(const void* g, void* l) {
  __builtin_amdgcn_global_load_lds(
      (const __attribute__((address_space(1))) unsigned int*)g,
      (__attribute__((address_space(3))) unsigned int*)l, 16, 0, 0);
}

__device__ __forceinline__ f32x4 mfma16x16x32(s16x8 a, s16x8 b, f32x4 c) {
  return __builtin_amdgcn_mfma_f32_16x16x32_bf16(a, b, c, 0, 0, 0);
}

__device__ __forceinline__ f32x16 mfma32x32x16(s16x8 a, s16x8 b, f32x16 c) {
  return __builtin_amdgcn_mfma_f32_32x32x16_bf16(a, b, c, 0, 0, 0);
}

__device__ __forceinline__ unsigned short bf16bits(float x) {
  __hip_bfloat16 h = __float2bfloat16(x);
  return *reinterpret_cast<unsigned short*>(&h);
}

// pack 2 f32 -> 2 bf16 (RNE), single instruction
__device__ __forceinline__ unsigned cvt_pk_bf16(float lo, float hi) {
  unsigned r;
  asm("v_cvt_pk_bf16_f32 %0, %1, %2" : "=v"(r) : "v"(lo), "v"(hi));
  return r;
}

// --- fused casts ---------------------------------------------------------
__global__ void cast3_kernel(const float* __restrict__ a,
                             const float* __restrict__ b,
                             const float* __restrict__ c,
                             __hip_bfloat16* oa, __hip_bfloat16* ob,
                             __hip_bfloat16* oc, int n4) {
  int i = blockIdx.x * blockDim.x + threadIdx.x;
  if (i >= n4) return;
  const float* in = blockIdx.y == 0 ? a : (blockIdx.y == 1 ? b : c);
  __hip_bfloat16* out = blockIdx.y == 0 ? oa : (blockIdx.y == 1 ? ob : oc);
  float4 v = ((const float4*)in)[i];
  ushort4 o;
  o.x = bf16bits(v.x);
  o.y = bf16bits(v.y);
  o.z = bf16bits(v.z);
  o.w = bf16bits(v.w);
  ((ushort4*)out)[i] = o;
}

__global__ void cast4_kernel(const float* __restrict__ a,
                             const float* __restrict__ b,
                             const float* __restrict__ c,
                             const float* __restrict__ d, __hip_bfloat16* oa,
                             __hip_bfloat16* ob, __hip_bfloat16* oc,
                             __hip_bfloat16* od, int n4) {
  int i = blockIdx.x * blockDim.x + threadIdx.x;
  if (i >= n4) return;
  const float* in = blockIdx.y == 0 ? a
                    : blockIdx.y == 1 ? b
                    : blockIdx.y == 2 ? c
                                      : d;
  __hip_bfloat16* out = blockIdx.y == 0 ? oa
                        : blockIdx.y == 1 ? ob
                        : blockIdx.y == 2 ? oc
                                          : od;
  float4 v = ((const float4*)in)[i];
  ushort4 o;
  o.x = bf16bits(v.x);
  o.y = bf16bits(v.y);
  o.z = bf16bits(v.z);
  o.w = bf16bits(v.w);
  ((ushort4*)out)[i] = o;
}

// --- mask -> bits: word gw covers mask[gw*64 .. gw*64+63] ----------------
__global__ void mask_bits_kernel(const int* __restrict__ mask,
                                 unsigned long long* __restrict__ bits) {
  int gw = (blockIdx.x * blockDim.x + threadIdx.x) >> 6;
  int lane = threadIdx.x & 63;
  int mv = mask[(size_t)gw * 64 + lane];
  unsigned long long b = __ballot(mv != 0);
  if (lane == 0) bits[gw] = b;
}

// --- fused QKV GEMM ------------------------------------------------------
// z=0: Qp = (q@Wq^T+bq)*0.125*log2e   (row-major bf16)
// z=1: Kp = (k@Wk^T+bk)               (row-major bf16)
// z=2: Vt = (v@Wv^T+bv) transposed to Vt[b,h,d,s]
__global__ __launch_bounds__(256) void gemm_qkv(
    const __hip_bfloat16* __restrict__ qb,
    const __hip_bfloat16* __restrict__ kb,
    const __hip_bfloat16* __restrict__ vb,
    const __hip_bfloat16* __restrict__ wq,
    const __hip_bfloat16* __restrict__ wk,
    const __hip_bfloat16* __restrict__ wv, const float* __restrict__ bq,
    const float* __restrict__ bk_, const float* __restrict__ bv_,
    __hip_bfloat16* __restrict__ Qp, __hip_bfloat16* __restrict__ Kp,
    __hip_bfloat16* __restrict__ Vtp) {
  constexpr int N = 1024, K = 1024;
  const int fid = blockIdx.x + 8 * (blockIdx.y + 32 * blockIdx.z);
  const int nid = (fid & 7) * 96 + (fid >> 3);
  const int bx = nid & 7;
  const int by = (nid >> 3) & 31;
  const int z = nid >> 8;

  const __hip_bfloat16* A = z == 0 ? qb : z == 1 ? kb : vb;
  const __hip_bfloat16* Bw = z == 0 ? wq : z == 1 ? wk : wv;
  const float* bias = z == 0 ? bq : z == 1 ? bk_ : bv_;

  __shared__ __hip_bfloat16 sA[128 * 32];
  __shared__ __hip_bfloat16 sB[128 * 32];
  const int tid = threadIdx.x;
  const int lane = tid & 63;
  const int wid = tid >> 6;
  const int wr = wid >> 1;
  const int wc = wid & 1;
  const int m0 = by * 128;
  const int n0 = bx * 128;
  const int srow = tid >> 2;
  const int scol = (tid & 3) * 8;

  f32x4 acc[4][4] = {};
  const int fr = lane & 15;
  const int fk = (lane >> 4) * 8;

  for (int k0 = 0; k0 < K; k0 += 32) {
    gload16(A + (size_t)(m0 + srow) * K + k0 + scol, sA + tid * 8);
    gload16(A + (size_t)(m0 + 64 + srow) * K + k0 + scol, sA + 2048 + tid * 8);
    gload16(Bw + (size_t)(n0 + srow) * K + k0 + scol, sB + tid * 8);
    gload16(Bw + (size_t)(n0 + 64 + srow) * K + k0 + scol, sB + 2048 + tid * 8);
    __syncthreads();
    s16x8 af[4], bfr[4];
#pragma unroll
    for (int mi = 0; mi < 4; ++mi)
      af[mi] = *(const s16x8*)(sA + (wr * 64 + mi * 16 + fr) * 32 + fk);
#pragma unroll
    for (int ni = 0; ni < 4; ++ni)
      bfr[ni] = *(const s16x8*)(sB + (wc * 64 + ni * 16 + fr) * 32 + fk);
#pragma unroll
    for (int mi = 0; mi < 4; ++mi)
#pragma unroll
      for (int ni = 0; ni < 4; ++ni)
        acc[mi][ni] = mfma16x16x32(af[mi], bfr[ni], acc[mi][ni]);
    __syncthreads();
  }

  const int fq = (lane >> 4) * 4;
#pragma unroll
  for (int mi = 0; mi < 4; ++mi) {
#pragma unroll
    for (int ni = 0; ni < 4; ++ni) {
      const int row = m0 + wr * 64 + mi * 16 + fq;
      const int col = n0 + wc * 64 + ni * 16 + fr;
      const float bv = bias[col];
      f32x4 v = acc[mi][ni];
      if (z == 2) {
        ushort4 pk;
        pk.x = bf16bits(v[0] + bv);
        pk.y = bf16bits(v[1] + bv);
        pk.z = bf16bits(v[2] + bv);
        pk.w = bf16bits(v[3] + bv);
        const int bb = row >> 11;
        const int s = row & 2047;
        size_t vtrow = ((size_t)(bb * 16) + (col >> 6)) * 64 + (col & 63);
        *(ushort4*)(Vtp + vtrow * 2048 + s) = pk;
      } else if (z == 1) {
#pragma unroll
        for (int r = 0; r < 4; ++r)
          Kp[(size_t)(row + r) * N + col] = __float2bfloat16(v[r] + bv);
      } else {
#pragma unroll
        for (int r = 0; r < 4; ++r)
          Qp[(size_t)(row + r) * N + col] =
              __float2bfloat16((v[r] + bv) * 0.18033688f);  // 0.125*log2(e)
      }
    }
  }
}

// --- out GEMM: C = A @ Bw^T + bias (f32 out) -----------------------------
__global__ __launch_bounds__(256) void gemm_out(
    const __hip_bfloat16* __restrict__ A, const __hip_bfloat16* __restrict__ Bw,
    const float* __restrict__ bias, float* __restrict__ Cout) {
  constexpr int N = 1024, K = 1024;
  const int fid = blockIdx.x + 8 * blockIdx.y;
  const int nid = (fid & 7) * 32 + (fid >> 3);
  const int bx = nid & 7;
  const int by = nid >> 3;

  __shared__ __hip_bfloat16 sA[128 * 32];
  __shared__ __hip_bfloat16 sB[128 * 32];
  const int tid = threadIdx.x;
  const int lane = tid & 63;
  const int wid = tid >> 6;
  const int wr = wid >> 1;
  const int wc = wid & 1;
  const int m0 = by * 128;
  const int n0 = bx * 128;
  const int srow = tid >> 2;
  const int scol = (tid & 3) * 8;

  f32x4 acc[4][4] = {};
  const int fr = lane & 15;
  const int fk = (lane >> 4) * 8;

  for (int k0 = 0; k0 < K; k0 += 32) {
    gload16(A + (size_t)(m0 + srow) * K + k0 + scol, sA + tid * 8);
    gload16(A + (size_t)(m0 + 64 + srow) * K + k0 + scol, sA + 2048 + tid * 8);
    gload16(Bw + (size_t)(n0 + srow) * K + k0 + scol, sB + tid * 8);
    gload16(Bw + (size_t)(n0 + 64 + srow) * K + k0 + scol, sB + 2048 + tid * 8);
    __syncthreads();
    s16x8 af[4], bfr[4];
#pragma unroll
    for (int mi = 0; mi < 4; ++mi)
      af[mi] = *(const s16x8*)(sA + (wr * 64 + mi * 16 + fr) * 32 + fk);
#pragma unroll
    for (int ni = 0; ni < 4; ++ni)
      bfr[ni] = *(const s16x8*)(sB + (wc * 64 + ni * 16 + fr) * 32 + fk);
#pragma unroll
    for (int mi = 0; mi < 4; ++mi)
#pragma unroll
      for (int ni = 0; ni < 4; ++ni)
        acc[mi][ni] = mfma16x16x32(af[mi], bfr[ni], acc[mi][ni]);
    __syncthreads();
  }

  const int fq = (lane >> 4) * 4;
#pragma unroll
  for (int mi = 0; mi < 4; ++mi) {
#pragma unroll
    for (int ni = 0; ni < 4; ++ni) {
      const int row = m0 + wr * 64 + mi * 16 + fq;
      const int col = n0 + wc * 64 + ni * 16 + fr;
      const float bv = bias[col];
      f32x4 v = acc[mi][ni];
#pragma unroll
      for (int r = 0; r < 4; ++r)
        Cout[(size_t)(row + r) * N + col] = v[r] + bv;
    }
  }
}

// --- flash attention: 32x32 MFMA, in-register P (permlane), dbuf LDS -----
// Block = (b,h) x 128 q-rows, 4 waves; wave owns 32 q (q = lane&31).
// Swapped QK^T (A=K, B=Q) => D[kv][q]: lane q=lane&31,
// kv = (reg&3) + 8*(reg>>2) + 4*h2 (h2 = lane>>5).
// P->bf16 via cvt_pk; PV A-fragments via v_permlane32_swap (d=even-b word).
// l via ones-MFMA (lacc rows == o rows). K/V: global_load_lds with
// pre-swizzled source into linear LDS; swizzled reads; dbuf, 1 barrier/tile.
__global__ __launch_bounds__(256) void attn_kernel(
    const __hip_bfloat16* __restrict__ Q, const __hip_bfloat16* __restrict__ Kb,
    const __hip_bfloat16* __restrict__ Vt,
    const unsigned long long* __restrict__ gbits,
    __hip_bfloat16* __restrict__ O, int S) {
  __shared__ __hip_bfloat16 sK[2][64 * 64];
  __shared__ __hip_bfloat16 sVT[2][64 * 64];

  const int tid = threadIdx.x;
  const int lane = tid & 63;
  const int wid = tid >> 6;  // 0..3
  // XCD-chunked swizzle: grid (16,32)=512, 64 nids (4 heads) per XCD
  const int fid = blockIdx.x + 16 * blockIdx.y;
  const int nid = (fid & 7) * 64 + (fid >> 3);
  const int qblk = nid & 15;
  const int bh = nid >> 4;
  const int q0 = qblk * 128;
  const int b = bh >> 4;
  const size_t rowbase = (size_t)b * S * 1024 + (size_t)(bh & 15) * 64;
  const size_t vtbase = (size_t)bh * 64;

  const int l31 = lane & 31;
  const int h2 = lane >> 5;

  // Q fragments (B-operand): lane provides Q[q=l31][d = c2*16 + h2*8 + j]
  const int qw = q0 + wid * 32 + l31;
  s16x8 aq[4];
#pragma unroll
  for (int c2 = 0; c2 < 4; ++c2)
    aq[c2] =
        *(const s16x8*)(Q + rowbase + (size_t)qw * 1024 + c2 * 16 + h2 * 8);

  f32x16 o0 = {}, o1 = {}, lacc = {};
  s16x8 ones;
#pragma unroll
  for (int j = 0; j < 8; ++j) ones[j] = (short)0x3F80;  // bf16 1.0

  // mask row for this lane's q
  const unsigned long long* bitrow = gbits + ((size_t)b * S + qw) * (S / 64);

  // staging: 8 regions of 8 rows each for K and for V; wave wid owns
  // regions {2wid, 2wid+1}. LDS linear = swizzled layout; source col-group
  // pre-swizzled: g_src = (lane&7) ^ (lane>>3).
  const int lrow = lane >> 3;               // 0..7 within region
  const int lg = ((lane & 7) ^ lrow) * 8;   // pre-swizzled source col (elems)
  auto STAGE = [&](int buf, int kv0) {
#pragma unroll
    for (int i = 0; i < 2; ++i) {
      const int rr = wid * 2 + i;
      const int rowi = rr * 8 + lrow;
      gload16(Kb + rowbase + (size_t)(kv0 + rowi) * 1024 + lg,
              &sK[buf][rr * 512 + lane * 8]);
      gload16(Vt + (vtbase + rowi) * 2048 + kv0 + lg,
              &sVT[buf][rr * 512 + lane * 8]);
    }
  };

  STAGE(0, 0);
  unsigned long long wcur = bitrow[0], wnxt = 0;

  const int ntiles = S / 64;
  for (int t = 0; t < ntiles; ++t) {
    const int cur = t & 1;
    __syncthreads();  // drain: buf[cur] loads complete for all waves

    if (t + 1 < ntiles) {
      STAGE(cur ^ 1, (t + 1) * 64);  // in flight during compute
      wnxt = bitrow[t + 1];
    }

    const __hip_bfloat16* sKc = &sK[cur][0];
    const __hip_bfloat16* sVc = &sVT[cur][0];

#pragma unroll
    for (int kt = 0; kt < 2; ++kt) {  // two 32-kv subtiles
      // QK^T: D[kv][q]
      f32x16 sc = {};
#pragma unroll
      for (int c2 = 0; c2 < 4; ++c2) {
        s16x8 ak = *(const s16x8*)(sKc + KSWZ(kt * 32 + l31, c2 * 16 + h2 * 8));
        sc = mfma32x32x16(ak, aq[c2], sc);
      }

      // P = mask ? exp2(S) : 0   (kv = (reg&3) + 8*(reg>>2) + 4*h2)
      const unsigned mm = (unsigned)(wcur >> (kt * 32 + h2 * 4));
      float p[16];
#pragma unroll
      for (int reg = 0; reg < 16; ++reg) {
        float e = EXP2F(sc[reg]);
        const int bit = (reg & 3) + 8 * (reg >> 2);
        p[reg] = ((mm >> bit) & 1u) ? e : 0.f;
      }

      // pack pairs: w[b_][t_] covers kv = 8b_ + 4h2 + 2t_ + {0,1}
      unsigned w0t0 = cvt_pk_bf16(p[0], p[1]), w0t1 = cvt_pk_bf16(p[2], p[3]);
      unsigned w1t0 = cvt_pk_bf16(p[4], p[5]), w1t1 = cvt_pk_bf16(p[6], p[7]);
      unsigned w2t0 = cvt_pk_bf16(p[8], p[9]), w2t1 = cvt_pk_bf16(p[10], p[11]);
      unsigned w3t0 = cvt_pk_bf16(p[12], p[13]),
               w3t1 = cvt_pk_bf16(p[14], p[15]);

      // swap(d=even-b word, s=odd-b word): d.hi <-> s.lo =>
      //   d' = {d.lo, s.lo} = A-frag word (j=0,1 | 2,3)
      //   s' = {d.hi, s.hi} = A-frag word (j=4,5 | 6,7)
      asm("v_permlane32_swap_b32 %0, %1" : "+v"(w0t0), "+v"(w1t0));
      asm("v_permlane32_swap_b32 %0, %1" : "+v"(w0t1), "+v"(w1t1));
      asm("v_permlane32_swap_b32 %0, %1" : "+v"(w2t0), "+v"(w3t0));
      asm("v_permlane32_swap_b32 %0, %1" : "+v"(w2t1), "+v"(w3t1));
      u32x4 qa0 = {w0t0, w0t1, w1t0, w1t1};
      u32x4 qa1 = {w2t0, w2t1, w3t0, w3t1};
      s16x8 A0 = __builtin_bit_cast(s16x8, qa0);
      s16x8 A1 = __builtin_bit_cast(s16x8, qa1);

      lacc = mfma32x32x16(A0, ones, lacc);
      lacc = mfma32x32x16(A1, ones, lacc);

      // PV: B = V[kv][d], lane reads sVT row d = dt*32+l31, kv chunk elems
      {
        s16x8 v00 = *(const s16x8*)(sVc + KSWZ(0 * 32 + l31, kt * 32 + h2 * 8));
        s16x8 v01 =
            *(const s16x8*)(sVc + KSWZ(0 * 32 + l31, kt * 32 + 16 + h2 * 8));
        o0 = mfma32x32x16(A0, v00, o0);
        o0 = mfma32x32x16(A1, v01, o0);
        s16x8 v10 = *(const s16x8*)(sVc + KSWZ(1 * 32 + l31, kt * 32 + h2 * 8));
        s16x8 v11 =
            *(const s16x8*)(sVc + KSWZ(1 * 32 + l31, kt * 32 + 16 + h2 * 8));
        o1 = mfma32x32x16(A0, v10, o1);
        o1 = mfma32x32x16(A1, v11, o1);
      }
    }
    wcur = wnxt;
  }

  // epilogue: q_r = (reg&3) + 8*(reg>>2) + 4*h2 ; d = dt*32 + l31
#pragma unroll
  for (int reg = 0; reg < 16; ++reg) {
    const float inv = RCPF(lacc[reg]);
    const int qr = (reg & 3) + 8 * (reg >> 2) + 4 * h2;
    const size_t base = rowbase + (size_t)(q0 + wid * 32 + qr) * 1024;
    O[base + 0 * 32 + l31] = __float2bfloat16(o0[reg] * inv);
    O[base + 1 * 32 + l31] = __float2bfloat16(o1[reg] * inv);
  }
}

extern "C" void kernel_launch(void* const* d_in, const int* in_sizes, int n_in,
                              void* d_out, int out_size, void* d_ws,
                              size_t ws_size, hipStream_t stream) {
  const float* query = (const float*)d_in[0];
  const float* key = (const float*)d_in[1];
  const float* value = (const float*)d_in[2];
  const int* mask = (const int*)d_in[3];
  const float* Wq = (const float*)d_in[4];
  const float* bq = (const float*)d_in[5];
  const float* Wk = (const float*)d_in[6];
  const float* bk = (const float*)d_in[7];
  const float* Wv = (const float*)d_in[8];
  const float* bv = (const float*)d_in[9];
  const float* Wo = (const float*)d_in[10];
  const float* bo = (const float*)d_in[11];

  const int B = 2, S = 2048, D = 1024;
  const int M = B * S;
  const size_t MB = 1024u * 1024u;

  char* ws = (char*)d_ws;
  __hip_bfloat16* qb = (__hip_bfloat16*)(ws + 0 * MB);
  __hip_bfloat16* kb = (__hip_bfloat16*)(ws + 8 * MB);
  __hip_bfloat16* vb = (__hip_bfloat16*)(ws + 16 * MB);
  __hip_bfloat16* wqb = (__hip_bfloat16*)(ws + 24 * MB);
  __hip_bfloat16* wkb = (__hip_bfloat16*)(ws + 26 * MB);
  __hip_bfloat16* wvb = (__hip_bfloat16*)(ws + 28 * MB);
  __hip_bfloat16* wob = (__hip_bfloat16*)(ws + 30 * MB);
  __hip_bfloat16* Qp = (__hip_bfloat16*)(ws + 32 * MB);
  __hip_bfloat16* Kp = (__hip_bfloat16*)(ws + 40 * MB);
  __hip_bfloat16* Vtp = (__hip_bfloat16*)(ws + 48 * MB);
  __hip_bfloat16* Ob = (__hip_bfloat16*)(ws + 56 * MB);
  unsigned long long* bits = (unsigned long long*)(ws + 64 * MB);

  {
    int n4 = (int)((size_t)M * D / 4);
    cast3_kernel<<<dim3((n4 + 255) / 256, 3), dim3(256), 0, stream>>>(
        query, key, value, qb, kb, vb, n4);
  }
  {
    int n4 = (int)((size_t)D * D / 4);
    cast4_kernel<<<dim3((n4 + 255) / 256, 4), dim3(256), 0, stream>>>(
        Wq, Wk, Wv, Wo, wqb, wkb, wvb, wob, n4);
  }
  {
    int words = B * S * (S / 64);  // 131072
    mask_bits_kernel<<<dim3(words / 4), dim3(256), 0, stream>>>(mask, bits);
  }

  gemm_qkv<<<dim3(D / 128, M / 128, 3), dim3(256), 0, stream>>>(
      qb, kb, vb, wqb, wkb, wvb, bq, bk, bv, Qp, Kp, Vtp);

  attn_kernel<<<dim3(S / 128, B * 16), dim3(256), 0, stream>>>(Qp, Kp, Vtp,
                                                               bits, Ob, S);

  gemm_out<<<dim3(D / 128, M / 128), dim3(256), 0, stream>>>(Ob, wob, bo,
                                                             (float*)d_out);
}

// Round 12
// 136.623 us; speedup vs baseline: 1.3621x; 1.0889x over previous
//
#include <hip/hip_runtime.h>
#include <hip/hip_bf16.h>

// B=2, S=2048, D=1024, H=16, hd=64.
// prep (fused casts + mask bitpack) -> fused QKV GEMM (Q pre-scaled by
// 0.125*log2e; K row-major; V transposed to Vt[b,h,d,s]) -> flash attention
// (32x32x16 MFMA, in-register P via cvt_pk+permlane32_swap, KVBLK=128 as
//  2x 64x64 swizzled sub-tiles, dbuf, ONE barrier per 128-kv tile,
//  no max-tracking: P=exp2(S) masked->0, l via ones-MFMA) -> out GEMM.

typedef float f32x4 __attribute__((ext_vector_type(4)));
typedef float f32x16 __attribute__((ext_vector_type(16)));
typedef short s16x8 __attribute__((ext_vector_type(8)));
typedef unsigned u32x4 __attribute__((ext_vector_type(4)));

#if __has_builtin(__builtin_amdgcn_exp2f)
#define EXP2F __builtin_amdgcn_exp2f
#else
#define EXP2F exp2f
#endif

#if __has_builtin(__builtin_amdgcn_rcpf)
#define RCPF __builtin_amdgcn_rcpf
#else
#define RCPF(x) (1.0f / (x))
#endif

// XOR swizzle for [64][64] bf16 LDS tiles: e = element col offset (mult of 8)
#define KSWZ(row, e) ((row) * 64 + ((e) ^ (((row) & 7) << 3)))

__device__ __forceinline__ void gload16(const void* g, void* l) {
  __builtin_amdgcn_global_load_lds(
      (const __attribute__((address_space(1))) unsigned int*)g,
      (__attribute__((address_space(3))) unsigned int*)l, 16, 0, 0);
}

__device__ __forceinline__ f32x4 mfma16x16x32(s16x8 a, s16x8 b, f32x4 c) {
  return __builtin_amdgcn_mfma_f32_16x16x32_bf16(a, b, c, 0, 0, 0);
}

__device__ __forceinline__ f32x16 mfma32x32x16(s16x8 a, s16x8 b, f32x16 c) {
  return __builtin_amdgcn_mfma_f32_32x32x16_bf16(a, b, c, 0, 0, 0);
}

__device__ __forceinline__ unsigned short bf16bits(float x) {
  __hip_bfloat16 h = __float2bfloat16(x);
  return *reinterpret_cast<unsigned short*>(&h);
}

// pack 2 f32 -> 2 bf16 (RNE), single instruction
__device__ __forceinline__ unsigned cvt_pk_bf16(float lo, float hi) {
  unsigned r;
  asm("v_cvt_pk_bf16_f32 %0, %1, %2" : "=v"(r) : "v"(lo), "v"(hi));
  return r;
}

// --- fused prep: casts (q,k,v,Wq,Wk,Wv,Wo -> bf16) + mask bitpack --------
__global__ __launch_bounds__(256) void prep_kernel(
    const float* __restrict__ q, const float* __restrict__ k,
    const float* __restrict__ v, const float* __restrict__ Wq,
    const float* __restrict__ Wk, const float* __restrict__ Wv,
    const float* __restrict__ Wo, const int* __restrict__ mask,
    __hip_bfloat16* qb, __hip_bfloat16* kb, __hip_bfloat16* vb,
    __hip_bfloat16* wqb, __hip_bfloat16* wkb, __hip_bfloat16* wvb,
    __hip_bfloat16* wob, unsigned long long* bits) {
  const int bid = blockIdx.x;
  if (bid < 16384) {
    // 4,194,304 float4s: 3x1,048,576 (q,k,v) + 4x262,144 (weights)
    int i = bid * 256 + threadIdx.x;
    const float* src;
    __hip_bfloat16* dst;
    int off;
    if (i < 3145728) {
      int seg = i >> 20;
      off = i & 1048575;
      src = seg == 0 ? q : seg == 1 ? k : v;
      dst = seg == 0 ? qb : seg == 1 ? kb : vb;
    } else {
      int j = i - 3145728;
      int seg = j >> 18;
      off = j & 262143;
      src = seg == 0 ? Wq : seg == 1 ? Wk : seg == 2 ? Wv : Wo;
      dst = seg == 0 ? wqb : seg == 1 ? wkb : seg == 2 ? wvb : wob;
    }
    float4 x = ((const float4*)src)[off];
    ushort4 o;
    o.x = bf16bits(x.x);
    o.y = bf16bits(x.y);
    o.z = bf16bits(x.z);
    o.w = bf16bits(x.w);
    ((ushort4*)dst)[off] = o;
  } else {
    // mask words: 131072 total; 16 per block (4 waves x 4 iters)
    const int base = (bid - 16384) * 16;
    const int wv_ = threadIdx.x >> 6;
    const int lane = threadIdx.x & 63;
#pragma unroll
    for (int it = 0; it < 4; ++it) {
      int gw = base + it * 4 + wv_;
      int mv = mask[(size_t)gw * 64 + lane];
      unsigned long long bm = __ballot(mv != 0);
      if (lane == 0) bits[gw] = bm;
    }
  }
}

// --- fused QKV GEMM ------------------------------------------------------
// z=0: Qp = (q@Wq^T+bq)*0.125*log2e   (row-major bf16)
// z=1: Kp = (k@Wk^T+bk)               (row-major bf16)
// z=2: Vt = (v@Wv^T+bv) transposed to Vt[b,h,d,s]
__global__ __launch_bounds__(256) void gemm_qkv(
    const __hip_bfloat16* __restrict__ qb,
    const __hip_bfloat16* __restrict__ kb,
    const __hip_bfloat16* __restrict__ vb,
    const __hip_bfloat16* __restrict__ wq,
    const __hip_bfloat16* __restrict__ wk,
    const __hip_bfloat16* __restrict__ wv, const float* __restrict__ bq,
    const float* __restrict__ bk_, const float* __restrict__ bv_,
    __hip_bfloat16* __restrict__ Qp, __hip_bfloat16* __restrict__ Kp,
    __hip_bfloat16* __restrict__ Vtp) {
  constexpr int N = 1024, K = 1024;
  const int fid = blockIdx.x + 8 * (blockIdx.y + 32 * blockIdx.z);
  const int nid = (fid & 7) * 96 + (fid >> 3);
  const int bx = nid & 7;
  const int by = (nid >> 3) & 31;
  const int z = nid >> 8;

  const __hip_bfloat16* A = z == 0 ? qb : z == 1 ? kb : vb;
  const __hip_bfloat16* Bw = z == 0 ? wq : z == 1 ? wk : wv;
  const float* bias = z == 0 ? bq : z == 1 ? bk_ : bv_;

  __shared__ __hip_bfloat16 sA[128 * 32];
  __shared__ __hip_bfloat16 sB[128 * 32];
  const int tid = threadIdx.x;
  const int lane = tid & 63;
  const int wid = tid >> 6;
  const int wr = wid >> 1;
  const int wc = wid & 1;
  const int m0 = by * 128;
  const int n0 = bx * 128;
  const int srow = tid >> 2;
  const int scol = (tid & 3) * 8;

  f32x4 acc[4][4] = {};
  const int fr = lane & 15;
  const int fk = (lane >> 4) * 8;

  for (int k0 = 0; k0 < K; k0 += 32) {
    gload16(A + (size_t)(m0 + srow) * K + k0 + scol, sA + tid * 8);
    gload16(A + (size_t)(m0 + 64 + srow) * K + k0 + scol, sA + 2048 + tid * 8);
    gload16(Bw + (size_t)(n0 + srow) * K + k0 + scol, sB + tid * 8);
    gload16(Bw + (size_t)(n0 + 64 + srow) * K + k0 + scol, sB + 2048 + tid * 8);
    __syncthreads();
    s16x8 af[4], bfr[4];
#pragma unroll
    for (int mi = 0; mi < 4; ++mi)
      af[mi] = *(const s16x8*)(sA + (wr * 64 + mi * 16 + fr) * 32 + fk);
#pragma unroll
    for (int ni = 0; ni < 4; ++ni)
      bfr[ni] = *(const s16x8*)(sB + (wc * 64 + ni * 16 + fr) * 32 + fk);
#pragma unroll
    for (int mi = 0; mi < 4; ++mi)
#pragma unroll
      for (int ni = 0; ni < 4; ++ni)
        acc[mi][ni] = mfma16x16x32(af[mi], bfr[ni], acc[mi][ni]);
    __syncthreads();
  }

  const int fq = (lane >> 4) * 4;
#pragma unroll
  for (int mi = 0; mi < 4; ++mi) {
#pragma unroll
    for (int ni = 0; ni < 4; ++ni) {
      const int row = m0 + wr * 64 + mi * 16 + fq;
      const int col = n0 + wc * 64 + ni * 16 + fr;
      const float bv = bias[col];
      f32x4 v = acc[mi][ni];
      if (z == 2) {
        ushort4 pk;
        pk.x = bf16bits(v[0] + bv);
        pk.y = bf16bits(v[1] + bv);
        pk.z = bf16bits(v[2] + bv);
        pk.w = bf16bits(v[3] + bv);
        const int bb = row >> 11;
        const int s = row & 2047;
        size_t vtrow = ((size_t)(bb * 16) + (col >> 6)) * 64 + (col & 63);
        *(ushort4*)(Vtp + vtrow * 2048 + s) = pk;
      } else if (z == 1) {
#pragma unroll
        for (int r = 0; r < 4; ++r)
          Kp[(size_t)(row + r) * N + col] = __float2bfloat16(v[r] + bv);
      } else {
#pragma unroll
        for (int r = 0; r < 4; ++r)
          Qp[(size_t)(row + r) * N + col] =
              __float2bfloat16((v[r] + bv) * 0.18033688f);  // 0.125*log2(e)
      }
    }
  }
}

// --- out GEMM: C = A @ Bw^T + bias (f32 out) -----------------------------
__global__ __launch_bounds__(256) void gemm_out(
    const __hip_bfloat16* __restrict__ A, const __hip_bfloat16* __restrict__ Bw,
    const float* __restrict__ bias, float* __restrict__ Cout) {
  constexpr int N = 1024, K = 1024;
  const int fid = blockIdx.x + 8 * blockIdx.y;
  const int nid = (fid & 7) * 32 + (fid >> 3);
  const int bx = nid & 7;
  const int by = nid >> 3;

  __shared__ __hip_bfloat16 sA[128 * 32];
  __shared__ __hip_bfloat16 sB[128 * 32];
  const int tid = threadIdx.x;
  const int lane = tid & 63;
  const int wid = tid >> 6;
  const int wr = wid >> 1;
  const int wc = wid & 1;
  const int m0 = by * 128;
  const int n0 = bx * 128;
  const int srow = tid >> 2;
  const int scol = (tid & 3) * 8;

  f32x4 acc[4][4] = {};
  const int fr = lane & 15;
  const int fk = (lane >> 4) * 8;

  for (int k0 = 0; k0 < K; k0 += 32) {
    gload16(A + (size_t)(m0 + srow) * K + k0 + scol, sA + tid * 8);
    gload16(A + (size_t)(m0 + 64 + srow) * K + k0 + scol, sA + 2048 + tid * 8);
    gload16(Bw + (size_t)(n0 + srow) * K + k0 + scol, sB + tid * 8);
    gload16(Bw + (size_t)(n0 + 64 + srow) * K + k0 + scol, sB + 2048 + tid * 8);
    __syncthreads();
    s16x8 af[4], bfr[4];
#pragma unroll
    for (int mi = 0; mi < 4; ++mi)
      af[mi] = *(const s16x8*)(sA + (wr * 64 + mi * 16 + fr) * 32 + fk);
#pragma unroll
    for (int ni = 0; ni < 4; ++ni)
      bfr[ni] = *(const s16x8*)(sB + (wc * 64 + ni * 16 + fr) * 32 + fk);
#pragma unroll
    for (int mi = 0; mi < 4; ++mi)
#pragma unroll
      for (int ni = 0; ni < 4; ++ni)
        acc[mi][ni] = mfma16x16x32(af[mi], bfr[ni], acc[mi][ni]);
    __syncthreads();
  }

  const int fq = (lane >> 4) * 4;
#pragma unroll
  for (int mi = 0; mi < 4; ++mi) {
#pragma unroll
    for (int ni = 0; ni < 4; ++ni) {
      const int row = m0 + wr * 64 + mi * 16 + fq;
      const int col = n0 + wc * 64 + ni * 16 + fr;
      const float bv = bias[col];
      f32x4 v = acc[mi][ni];
#pragma unroll
      for (int r = 0; r < 4; ++r)
        Cout[(size_t)(row + r) * N + col] = v[r] + bv;
    }
  }
}

// --- flash attention: 32x32 MFMA, in-register P, KVBLK=128, dbuf ---------
// Block = (b,h) x 128 q-rows, 4 waves; wave owns 32 q (q = lane&31).
// KV tile = 128 rows as 2x 64x64 swizzled sub-tiles (same verified KSWZ
// pattern on both halves). ONE barrier per 128-kv tile (16 total).
// Swapped QK^T (A=K, B=Q) => D[kv][q]; in-register P via cvt_pk +
// permlane32_swap; l via ones-MFMA.
__global__ __launch_bounds__(256) void attn_kernel(
    const __hip_bfloat16* __restrict__ Q, const __hip_bfloat16* __restrict__ Kb,
    const __hip_bfloat16* __restrict__ Vt,
    const unsigned long long* __restrict__ gbits,
    __hip_bfloat16* __restrict__ O, int S) {
  __shared__ __hip_bfloat16 sK[2][2][64 * 64];   // [buf][kv-half][kv][d]
  __shared__ __hip_bfloat16 sVT[2][2][64 * 64];  // [buf][kv-half][d][kv]

  const int tid = threadIdx.x;
  const int lane = tid & 63;
  const int wid = tid >> 6;  // 0..3
  // XCD-chunked swizzle: grid (16,32)=512, 64 nids (4 heads) per XCD
  const int fid = blockIdx.x + 16 * blockIdx.y;
  const int nid = (fid & 7) * 64 + (fid >> 3);
  const int qblk = nid & 15;
  const int bh = nid >> 4;
  const int q0 = qblk * 128;
  const int b = bh >> 4;
  const size_t rowbase = (size_t)b * S * 1024 + (size_t)(bh & 15) * 64;
  const size_t vtbase = (size_t)bh * 64;

  const int l31 = lane & 31;
  const int h2 = lane >> 5;

  // Q fragments (B-operand): lane provides Q[q=l31][d = c2*16 + h2*8 + j]
  const int qw = q0 + wid * 32 + l31;
  s16x8 aq[4];
#pragma unroll
  for (int c2 = 0; c2 < 4; ++c2)
    aq[c2] =
        *(const s16x8*)(Q + rowbase + (size_t)qw * 1024 + c2 * 16 + h2 * 8);

  f32x16 o0 = {}, o1 = {}, lacc = {};
  s16x8 ones;
#pragma unroll
  for (int j = 0; j < 8; ++j) ones[j] = (short)0x3F80;  // bf16 1.0

  // mask row for this lane's q (2 u64 words per 128-kv tile)
  const unsigned long long* bitrow = gbits + ((size_t)b * S + qw) * (S / 64);

  // staging: per half, 8 regions of 8 rows; wave wid owns regions
  // {2wid, 2wid+1}. Linear LDS dest + pre-swizzled global source col.
  const int lrow = lane >> 3;              // 0..7 within region
  const int lg = ((lane & 7) ^ lrow) * 8;  // pre-swizzled source col (elems)
  auto STAGE = [&](int buf, int kv0) {
#pragma unroll
    for (int h = 0; h < 2; ++h) {
#pragma unroll
      for (int i = 0; i < 2; ++i) {
        const int rr = wid * 2 + i;
        const int rowi = rr * 8 + lrow;  // 0..63 within half
        gload16(Kb + rowbase + (size_t)(kv0 + h * 64 + rowi) * 1024 + lg,
                &sK[buf][h][rr * 512 + lane * 8]);
        gload16(Vt + (vtbase + rowi) * 2048 + kv0 + h * 64 + lg,
                &sVT[buf][h][rr * 512 + lane * 8]);
      }
    }
  };

  STAGE(0, 0);
  unsigned long long wc0 = bitrow[0], wc1 = bitrow[1];
  unsigned long long wn0 = 0, wn1 = 0;

  const int ntiles = S / 128;  // 16
  for (int t = 0; t < ntiles; ++t) {
    const int cur = t & 1;
    __syncthreads();  // drain: buf[cur] loads complete for all waves

    if (t + 1 < ntiles) {
      STAGE(cur ^ 1, (t + 1) * 128);  // in flight during compute
      wn0 = bitrow[2 * t + 2];
      wn1 = bitrow[2 * t + 3];
    }

#pragma unroll
    for (int kt = 0; kt < 4; ++kt) {  // four 32-kv subtiles
      const int kh = kt >> 1, kp = kt & 1;
      const __hip_bfloat16* sKc = &sK[cur][kh][0];
      const __hip_bfloat16* sVc = &sVT[cur][kh][0];

      // QK^T: D[kv][q]
      f32x16 sc = {};
#pragma unroll
      for (int c2 = 0; c2 < 4; ++c2) {
        s16x8 ak = *(const s16x8*)(sKc + KSWZ(kp * 32 + l31, c2 * 16 + h2 * 8));
        sc = mfma32x32x16(ak, aq[c2], sc);
      }

      // P = mask ? exp2(S) : 0   (kv bit = (reg&3) + 8*(reg>>2))
      const unsigned long long wcv = kh ? wc1 : wc0;
      const unsigned mm = (unsigned)(wcv >> (kp * 32 + h2 * 4));
      float p[16];
#pragma unroll
      for (int reg = 0; reg < 16; ++reg) {
        float e = EXP2F(sc[reg]);
        const int bit = (reg & 3) + 8 * (reg >> 2);
        p[reg] = ((mm >> bit) & 1u) ? e : 0.f;
      }

      unsigned w0t0 = cvt_pk_bf16(p[0], p[1]), w0t1 = cvt_pk_bf16(p[2], p[3]);
      unsigned w1t0 = cvt_pk_bf16(p[4], p[5]), w1t1 = cvt_pk_bf16(p[6], p[7]);
      unsigned w2t0 = cvt_pk_bf16(p[8], p[9]), w2t1 = cvt_pk_bf16(p[10], p[11]);
      unsigned w3t0 = cvt_pk_bf16(p[12], p[13]),
               w3t1 = cvt_pk_bf16(p[14], p[15]);

      // swap(d=even-b word, s=odd-b word): d.hi <-> s.lo
      asm("v_permlane32_swap_b32 %0, %1" : "+v"(w0t0), "+v"(w1t0));
      asm("v_permlane32_swap_b32 %0, %1" : "+v"(w0t1), "+v"(w1t1));
      asm("v_permlane32_swap_b32 %0, %1" : "+v"(w2t0), "+v"(w3t0));
      asm("v_permlane32_swap_b32 %0, %1" : "+v"(w2t1), "+v"(w3t1));
      u32x4 qa0 = {w0t0, w0t1, w1t0, w1t1};
      u32x4 qa1 = {w2t0, w2t1, w3t0, w3t1};
      s16x8 A0 = __builtin_bit_cast(s16x8, qa0);
      s16x8 A1 = __builtin_bit_cast(s16x8, qa1);

      lacc = mfma32x32x16(A0, ones, lacc);
      lacc = mfma32x32x16(A1, ones, lacc);

      // PV: B = V[kv][d], lane reads sVT row d = dt*32+l31
      {
        s16x8 v00 = *(const s16x8*)(sVc + KSWZ(0 * 32 + l31, kp * 32 + h2 * 8));
        s16x8 v01 =
            *(const s16x8*)(sVc + KSWZ(0 * 32 + l31, kp * 32 + 16 + h2 * 8));
        o0 = mfma32x32x16(A0, v00, o0);
        o0 = mfma32x32x16(A1, v01, o0);
        s16x8 v10 = *(const s16x8*)(sVc + KSWZ(1 * 32 + l31, kp * 32 + h2 * 8));
        s16x8 v11 =
            *(const s16x8*)(sVc + KSWZ(1 * 32 + l31, kp * 32 + 16 + h2 * 8));
        o1 = mfma32x32x16(A0, v10, o1);
        o1 = mfma32x32x16(A1, v11, o1);
      }
    }
    wc0 = wn0;
    wc1 = wn1;
  }

  // epilogue: q_r = (reg&3) + 8*(reg>>2) + 4*h2 ; d = dt*32 + l31
#pragma unroll
  for (int reg = 0; reg < 16; ++reg) {
    const float inv = RCPF(lacc[reg]);
    const int qr = (reg & 3) + 8 * (reg >> 2) + 4 * h2;
    const size_t base = rowbase + (size_t)(q0 + wid * 32 + qr) * 1024;
    O[base + 0 * 32 + l31] = __float2bfloat16(o0[reg] * inv);
    O[base + 1 * 32 + l31] = __float2bfloat16(o1[reg] * inv);
  }
}

extern "C" void kernel_launch(void* const* d_in, const int* in_sizes, int n_in,
                              void* d_out, int out_size, void* d_ws,
                              size_t ws_size, hipStream_t stream) {
  const float* query = (const float*)d_in[0];
  const float* key = (const float*)d_in[1];
  const float* value = (const float*)d_in[2];
  const int* mask = (const int*)d_in[3];
  const float* Wq = (const float*)d_in[4];
  const float* bq = (const float*)d_in[5];
  const float* Wk = (const float*)d_in[6];
  const float* bk = (const float*)d_in[7];
  const float* Wv = (const float*)d_in[8];
  const float* bv = (const float*)d_in[9];
  const float* Wo = (const float*)d_in[10];
  const float* bo = (const float*)d_in[11];

  const int B = 2, S = 2048, D = 1024;
  const int M = B * S;
  const size_t MB = 1024u * 1024u;

  char* ws = (char*)d_ws;
  __hip_bfloat16* qb = (__hip_bfloat16*)(ws + 0 * MB);
  __hip_bfloat16* kb = (__hip_bfloat16*)(ws + 8 * MB);
  __hip_bfloat16* vb = (__hip_bfloat16*)(ws + 16 * MB);
  __hip_bfloat16* wqb = (__hip_bfloat16*)(ws + 24 * MB);
  __hip_bfloat16* wkb = (__hip_bfloat16*)(ws + 26 * MB);
  __hip_bfloat16* wvb = (__hip_bfloat16*)(ws + 28 * MB);
  __hip_bfloat16* wob = (__hip_bfloat16*)(ws + 30 * MB);
  __hip_bfloat16* Qp = (__hip_bfloat16*)(ws + 32 * MB);
  __hip_bfloat16* Kp = (__hip_bfloat16*)(ws + 40 * MB);
  __hip_bfloat16* Vtp = (__hip_bfloat16*)(ws + 48 * MB);
  __hip_bfloat16* Ob = (__hip_bfloat16*)(ws + 56 * MB);
  unsigned long long* bits = (unsigned long long*)(ws + 64 * MB);

  // 16384 cast blocks + 8192 mask blocks
  prep_kernel<<<dim3(24576), dim3(256), 0, stream>>>(
      query, key, value, Wq, Wk, Wv, Wo, mask, qb, kb, vb, wqb, wkb, wvb, wob,
      bits);

  gemm_qkv<<<dim3(D / 128, M / 128, 3), dim3(256), 0, stream>>>(
      qb, kb, vb, wqb, wkb, wvb, bq, bk, bv, Qp, Kp, Vtp);

  attn_kernel<<<dim3(S / 128, B * 16), dim3(256), 0, stream>>>(Qp, Kp, Vtp,
                                                               bits, Ob, S);

  gemm_out<<<dim3(D / 128, M / 128), dim3(256), 0, stream>>>(Ob, wob, bo,
                                                             (float*)d_out);
}